// Round 14
// baseline (176.849 us; speedup 1.0000x reference)
//
#include <hip/hip_runtime.h>
#include <cstdint>
#include <cstddef>

#define NB 2048
#define NT 512
#define ND 64
#define NR 50
#define REVP 68          // review row stride (floats)
#define ALDS 25600       // A-half LDS bytes: 50 rows x 512B (256 bf16)

typedef __attribute__((ext_vector_type(8))) short bf16x8;
typedef __attribute__((ext_vector_type(4))) float f32x4;

__device__ inline unsigned short f2bf_rne(float x) {
    unsigned int u = __float_as_uint(x);
    u += 0x7fffu + ((u >> 16) & 1u);
    return (unsigned short)(u >> 16);
}

__device__ inline bf16x8 cvt8_rne(float4 v0, float4 v1) {
    union { unsigned int u[4]; bf16x8 v; } P;
    asm("v_cvt_pk_bf16_f32 %0, %1, %2" : "=v"(P.u[0]) : "v"(v0.x), "v"(v0.y));
    asm("v_cvt_pk_bf16_f32 %0, %1, %2" : "=v"(P.u[1]) : "v"(v0.z), "v"(v0.w));
    asm("v_cvt_pk_bf16_f32 %0, %1, %2" : "=v"(P.u[2]) : "v"(v1.x), "v"(v1.y));
    asm("v_cvt_pk_bf16_f32 %0, %1, %2" : "=v"(P.u[3]) : "v"(v1.z), "v"(v1.w));
    return P.v;
}

__device__ inline void gload16(const void* gsrc, void* ldst) {
    __builtin_amdgcn_global_load_lds(
        (const __attribute__((address_space(1))) unsigned int*)gsrc,
        (__attribute__((address_space(3))) unsigned int*)ldst, 16, 0, 0);
}

// ---------------------------------------------------------------------------
// Pack topic_w into main-GEMM B-frag order (single bf16, RNE) and fc weights
// into epilogue B-frag order (K=128: rows 0-63 = fc_r_w, 64-127 = fc_a_w).
__global__ __launch_bounds__(256) void prep_kernel(
    const float* __restrict__ tw,
    const float* __restrict__ fc_u_w, const float* __restrict__ fc_ru_w,
    const float* __restrict__ fc_i_w, const float* __restrict__ fc_ri_w,
    unsigned short* __restrict__ bhi,
    unsigned short* __restrict__ fuhi, unsigned short* __restrict__ fihi)
{
    int i = blockIdx.x * 256 + threadIdx.x;          // 192*256 = 49152
    if (i < 32768) {
        int j  = i & 7;
        int l  = (i >> 3) & 63;
        int n  = (i >> 9) & 3;
        int kk = i >> 11;                            // 0..15
        int t = kk * 32 + ((l >> 4) << 3) + j;
        int d = n * 16 + (l & 15);
        bhi[i] = f2bf_rne(tw[t * ND + d]);
    } else {
        int q = i - 32768;                           // 0..16383
        int br = q >> 13;                            // 0 user, 1 item
        int e = q & 8191;
        int j  = e & 7;
        int l  = (e >> 3) & 63;
        int n  = (e >> 9) & 3;
        int kk = e >> 11;                            // 0..3
        int k = kk * 32 + ((l >> 4) << 3) + j;       // 0..127
        int col = n * 16 + (l & 15);
        const float* W = (k < 64) ? (br ? fc_ri_w : fc_ru_w)
                                  : (br ? fc_i_w  : fc_u_w);
        unsigned short hi = f2bf_rne(W[(k & 63) * ND + col]);
        if (br) fihi[e] = hi; else fuhi[e] = hi;
    }
}

// ---------------------------------------------------------------------------
__global__ __launch_bounds__(256) void colsum_kernel(const float* __restrict__ tw,
                                                     float* __restrict__ colsum) {
    __shared__ float part[4][ND];
    int d = threadIdx.x & 63, p = threadIdx.x >> 6;
    float s = 0.f;
    for (int t = p; t < NT; t += 4) s += tw[t * ND + d];
    part[p][d] = s;
    __syncthreads();
    if (threadIdx.x < ND)
        colsum[d] = part[0][d] + part[1][d] + part[2][d] + part[3][d];
}

// ---------------------------------------------------------------------------
// One block per (branch, batch element), 4 waves, 2 blocks/CU, 256-VGPR budget.
// Per K-half: STREAM phase (copy-shaped: each wave instruction reads 1KB
// CONTIGUOUS -- lane l reads float4 at row_base + l*16B; 13 independent
// iterations -> deep compiler pipelining) + B-half via global_load_lds.
// Then COMPUTE phase: pure LDS->MFMA, zero vmem.
__global__ __launch_bounds__(256, 2) void branch_kernel(
    const int* __restrict__ user, const int* __restrict__ item,
    const float* __restrict__ user_r_topic, const float* __restrict__ item_r_topic,
    const float* __restrict__ user_embed_w, const float* __restrict__ item_embed_w,
    const float* __restrict__ user_att_w, const float* __restrict__ item_att_w,
    const unsigned short* __restrict__ bhi,
    const unsigned short* __restrict__ fuhi, const unsigned short* __restrict__ fihi,
    const float* __restrict__ fc_u_b, const float* __restrict__ fc_ru_b,
    const float* __restrict__ fc_i_b, const float* __restrict__ fc_ri_b,
    const float* __restrict__ h_u_w, const float* __restrict__ h_u_b,
    const float* __restrict__ h_i_w, const float* __restrict__ h_i_b,
    const float* __restrict__ colsum,
    float* __restrict__ u_vec, float* __restrict__ i_vec)
{
    // arena: A-half bf16 (swizzled) [0, 25600) | B-half frag order [25600, 58368)
    // rev[50][68] f32 overlays the B region after the K-loop.
    __shared__ __align__(16) unsigned char arena[ALDS + 32768];
    __shared__ float lds_logit[NR + 2];

    const int tid = threadIdx.x, wave = tid >> 6, lane = tid & 63;
    const int g = lane >> 4, c16 = lane & 15;

    const int bb = blockIdx.x;
    const int branch = bb >> 11;          // 0 = user, 1 = item
    const int b = bb & (NB - 1);

    const int*   ids     = branch ? item           : user;
    const float* r_topic = branch ? item_r_topic   : user_r_topic;
    const float* emb_w   = branch ? item_embed_w   : user_embed_w;
    const float* att_w   = branch ? item_att_w     : user_att_w;
    const unsigned short* fhi = branch ? fihi : fuhi;
    const float* fc_a_b  = branch ? fc_i_b         : fc_u_b;
    const float* fc_r_b  = branch ? fc_ri_b        : fc_ru_b;
    const float* h_w     = branch ? h_i_w          : h_u_w;
    const float* h_b     = branch ? h_i_b          : h_u_b;
    float*       out_vec = branch ? i_vec          : u_vec;

    const int id = ids[b];
    const int rowg = wave * 16 + c16;
    const int rowc = rowg < NR ? rowg : NR - 1;
    unsigned char* blds = arena + ALDS;

    const float* Abase = r_topic + (size_t)b * NR * NT;

    // STREAM phase for half h: A rows col-window [h*256, h*256+256) -> bf16 LDS.
    // Wave w handles rows w, w+4, ..., one row per iteration, 1KB contiguous.
    auto streamA = [&](int h) {
#pragma unroll
        for (int i = 0; i < 13; ++i) {
            int row = i * 4 + wave;
            if (row < NR) {                          // wave-uniform guard
                float4 v = *reinterpret_cast<const float4*>(
                    Abase + (size_t)row * NT + h * 256 + lane * 4);
                unsigned int d0, d1;
                asm("v_cvt_pk_bf16_f32 %0, %1, %2" : "=v"(d0) : "v"(v.x), "v"(v.y));
                asm("v_cvt_pk_bf16_f32 %0, %1, %2" : "=v"(d1) : "v"(v.z), "v"(v.w));
                int s = lane ^ ((row & 7) << 1);     // 8B-slot XOR swizzle
                uint2 w2; w2.x = d0; w2.y = d1;
                *reinterpret_cast<uint2*>(arena + row * 512 + s * 8) = w2;
            }
        }
    };
    auto stageB = [&](int h) {
        const unsigned char* src = (const unsigned char*)bhi + (size_t)h * 32768;
#pragma unroll
        for (int i = 0; i < 8; ++i) {
            size_t off = (size_t)(i * 256 + tid) * 16;
            gload16(src + off, blds + off);
        }
    };

    f32x4 acc[4];
#pragma unroll
    for (int n = 0; n < 4; ++n) acc[n] = (f32x4){0.f, 0.f, 0.f, 0.f};

    // COMPUTE step (kkl = 0..7 within half): pure LDS.
    auto kstep = [&](int kkl) {
        bf16x8 af = *reinterpret_cast<const bf16x8*>(
            arena + rowc * 512 + (((kkl * 4 + g) ^ (rowc & 7)) << 4));
#pragma unroll
        for (int n = 0; n < 4; ++n) {
            bf16x8 bh = *reinterpret_cast<const bf16x8*>(
                blds + (size_t)((kkl * 4 + n) * 64 + lane) * 16);
            acc[n] = __builtin_amdgcn_mfma_f32_16x16x32_bf16(af, bh, acc[n], 0, 0, 0);
        }
    };

    stageB(0);
    streamA(0);
    __syncthreads();                      // half0 A+B resident
#pragma unroll
    for (int kkl = 0; kkl < 8; ++kkl) kstep(kkl);
    __syncthreads();                      // all reads of half0 done
    stageB(1);
    streamA(1);
    __syncthreads();                      // half1 A+B resident
#pragma unroll
    for (int kkl = 0; kkl < 8; ++kkl) kstep(kkl);

    __syncthreads();                      // all LDS reads done -> overlay rev
    float (*rev)[REVP] = reinterpret_cast<float(*)[REVP]>(blds);
#pragma unroll
    for (int n = 0; n < 4; ++n)
#pragma unroll
        for (int r4 = 0; r4 < 4; ++r4) {
            int r = wave * 16 + g * 4 + r4;
            if (r < NR) rev[r][n * 16 + c16] = acc[n][r4];
        }
    // no barrier: epilogue reads only this wave's own rows

    // ---- epilogue s-matmul: s[50x64] = review@fcR + att@fcA (K=128, bf16) ----
    f32x4 s4[4];
#pragma unroll
    for (int n = 0; n < 4; ++n) s4[n] = (f32x4){0.f, 0.f, 0.f, 0.f};

#pragma unroll
    for (int kk2 = 0; kk2 < 4; ++kk2) {
        bf16x8 bh[4];
#pragma unroll
        for (int n = 0; n < 4; ++n)
            bh[n] = *(reinterpret_cast<const bf16x8*>(fhi + (size_t)(kk2 * 4 + n) * 512) + lane);
        bf16x8 ah;
        if (kk2 < 2) {
            const float* rp = &rev[rowc][kk2 * 32 + g * 8];
            ah = cvt8_rne(*reinterpret_cast<const float4*>(rp),
                          *reinterpret_cast<const float4*>(rp + 4));
        } else {
            const float* ap = att_w + (size_t)id * ND + (kk2 - 2) * 32 + g * 8;
            ah = cvt8_rne(*reinterpret_cast<const float4*>(ap),
                          *reinterpret_cast<const float4*>(ap + 4));
        }
#pragma unroll
        for (int n = 0; n < 4; ++n)
            s4[n] = __builtin_amdgcn_mfma_f32_16x16x32_bf16(ah, bh[n], s4[n], 0, 0, 0);
    }

    // bias + relu + dot with h_w, then 16-lane reduce -> logits
    const float hb = h_b[0];
    float p0 = 0.f, p1 = 0.f, p2 = 0.f, p3 = 0.f;
#pragma unroll
    for (int n = 0; n < 4; ++n) {
        float hwn = h_w[n * 16 + c16];
        float bs = fc_r_b[n * 16 + c16] + fc_a_b[n * 16 + c16];
        p0 = fmaf(fmaxf(s4[n][0] + bs, 0.f), hwn, p0);
        p1 = fmaf(fmaxf(s4[n][1] + bs, 0.f), hwn, p1);
        p2 = fmaf(fmaxf(s4[n][2] + bs, 0.f), hwn, p2);
        p3 = fmaf(fmaxf(s4[n][3] + bs, 0.f), hwn, p3);
    }
#pragma unroll
    for (int off = 1; off < 16; off <<= 1) {
        p0 += __shfl_xor(p0, off);
        p1 += __shfl_xor(p1, off);
        p2 += __shfl_xor(p2, off);
        p3 += __shfl_xor(p3, off);
    }
    if (c16 == 0) {
        int rb = wave * 16 + g * 4;
        if (rb + 0 < NR) lds_logit[rb + 0] = p0 + hb;
        if (rb + 1 < NR) lds_logit[rb + 1] = p1 + hb;
        if (rb + 2 < NR) lds_logit[rb + 2] = p2 + hb;
        if (rb + 3 < NR) lds_logit[rb + 3] = p3 + hb;
    }
    __syncthreads();   // publish rev rows + logits to wave 0

    // softmax + pooling + colsum scale + emb add (wave 0)
    if (wave == 0) {
        float m = -1e30f;
        for (int r = 0; r < NR; ++r) m = fmaxf(m, lds_logit[r]);
        float sum = 0.f;
        for (int r = 0; r < NR; ++r) sum += __expf(lds_logit[r] - m);
        float inv = 1.f / sum;
        float feat = 0.f;
        for (int r = 0; r < NR; ++r)
            feat = fmaf(__expf(lds_logit[r] - m), rev[r][lane], feat);
        feat *= inv;
        out_vec[(size_t)b * ND + lane] = feat * colsum[lane] + emb_w[(size_t)id * ND + lane];
    }
}

// ---------------------------------------------------------------------------
__global__ __launch_bounds__(64) void final_kernel(
    const float* __restrict__ u_vec, const float* __restrict__ i_vec,
    const float* __restrict__ fc_pre_w, const float* __restrict__ fc_pre_b,
    float* __restrict__ out)
{
    int b = blockIdx.x, lane = threadIdx.x;
    float v = u_vec[(size_t)b * ND + lane] * fc_pre_w[lane]
            + i_vec[(size_t)b * ND + lane] * fc_pre_w[ND + lane];
#pragma unroll
    for (int off = 32; off; off >>= 1) v += __shfl_xor(v, off);
    if (lane == 0) out[b] = fmaxf(v + fc_pre_b[0], 0.f);
}

// ---------------------------------------------------------------------------
extern "C" void kernel_launch(void* const* d_in, const int* in_sizes, int n_in,
                              void* d_out, int out_size, void* d_ws, size_t ws_size,
                              hipStream_t stream) {
    (void)in_sizes; (void)n_in; (void)out_size; (void)ws_size;

    const int*   user         = (const int*)d_in[0];
    const int*   item         = (const int*)d_in[1];
    const float* user_r_topic = (const float*)d_in[2];
    const float* item_r_topic = (const float*)d_in[3];
    const float* user_embed_w = (const float*)d_in[4];
    const float* item_embed_w = (const float*)d_in[5];
    const float* user_att_w   = (const float*)d_in[6];
    const float* item_att_w   = (const float*)d_in[7];
    const float* topic_w      = (const float*)d_in[8];
    const float* fc_u_w       = (const float*)d_in[9];
    const float* fc_u_b       = (const float*)d_in[10];
    const float* fc_ru_w      = (const float*)d_in[11];
    const float* fc_ru_b      = (const float*)d_in[12];
    const float* fc_i_w       = (const float*)d_in[13];
    const float* fc_i_b       = (const float*)d_in[14];
    const float* fc_ri_w      = (const float*)d_in[15];
    const float* fc_ri_b      = (const float*)d_in[16];
    const float* h_u_w        = (const float*)d_in[17];
    const float* h_u_b        = (const float*)d_in[18];
    const float* h_i_w        = (const float*)d_in[19];
    const float* h_i_b        = (const float*)d_in[20];
    const float* fc_pre_w     = (const float*)d_in[21];
    const float* fc_pre_b     = (const float*)d_in[22];

    // workspace layout
    unsigned short* bhi  = (unsigned short*)d_ws;      // 32768
    unsigned short* fuhi = bhi + 32768;                // 8192
    unsigned short* fihi = fuhi + 8192;                // 8192
    float* colsum = (float*)(fihi + 8192);             // 64
    float* u_vec  = colsum + 64;                       // NB*ND
    float* i_vec  = u_vec + NB * ND;                   // NB*ND

    prep_kernel<<<192, 256, 0, stream>>>(topic_w, fc_u_w, fc_ru_w, fc_i_w, fc_ri_w,
                                         bhi, fuhi, fihi);
    colsum_kernel<<<1, 256, 0, stream>>>(topic_w, colsum);

    branch_kernel<<<2 * NB, 256, 0, stream>>>(
        user, item, user_r_topic, item_r_topic,
        user_embed_w, item_embed_w, user_att_w, item_att_w,
        bhi, fuhi, fihi,
        fc_u_b, fc_ru_b, fc_i_b, fc_ri_b,
        h_u_w, h_u_b, h_i_w, h_i_b,
        colsum, u_vec, i_vec);

    final_kernel<<<NB, 64, 0, stream>>>(u_vec, i_vec, fc_pre_w, fc_pre_b,
                                        (float*)d_out);
}

// Round 15
// 134.726 us; speedup vs baseline: 1.3127x; 1.3127x over previous
//
#include <hip/hip_runtime.h>
#include <cstdint>
#include <cstddef>

#define NB 2048
#define NT 512
#define ND 64
#define NR 50
#define REVP 68          // review row stride (floats)
#define ALDS 25600       // A-half LDS bytes: 50 rows x 512B (256 bf16)

typedef __attribute__((ext_vector_type(8))) short bf16x8;
typedef __attribute__((ext_vector_type(4))) float f32x4;

__device__ inline unsigned short f2bf_rne(float x) {
    unsigned int u = __float_as_uint(x);
    u += 0x7fffu + ((u >> 16) & 1u);
    return (unsigned short)(u >> 16);
}

__device__ inline bf16x8 cvt8_rne(float4 v0, float4 v1) {
    union { unsigned int u[4]; bf16x8 v; } P;
    asm("v_cvt_pk_bf16_f32 %0, %1, %2" : "=v"(P.u[0]) : "v"(v0.x), "v"(v0.y));
    asm("v_cvt_pk_bf16_f32 %0, %1, %2" : "=v"(P.u[1]) : "v"(v0.z), "v"(v0.w));
    asm("v_cvt_pk_bf16_f32 %0, %1, %2" : "=v"(P.u[2]) : "v"(v1.x), "v"(v1.y));
    asm("v_cvt_pk_bf16_f32 %0, %1, %2" : "=v"(P.u[3]) : "v"(v1.z), "v"(v1.w));
    return P.v;
}

__device__ inline void gload16(const void* gsrc, void* ldst) {
    __builtin_amdgcn_global_load_lds(
        (const __attribute__((address_space(1))) unsigned int*)gsrc,
        (__attribute__((address_space(3))) unsigned int*)ldst, 16, 0, 0);
}

// ---------------------------------------------------------------------------
__global__ __launch_bounds__(256) void prep_kernel(
    const float* __restrict__ tw,
    const float* __restrict__ fc_u_w, const float* __restrict__ fc_ru_w,
    const float* __restrict__ fc_i_w, const float* __restrict__ fc_ri_w,
    unsigned short* __restrict__ bhi,
    unsigned short* __restrict__ fuhi, unsigned short* __restrict__ fihi)
{
    int i = blockIdx.x * 256 + threadIdx.x;          // 192*256 = 49152
    if (i < 32768) {
        int j  = i & 7;
        int l  = (i >> 3) & 63;
        int n  = (i >> 9) & 3;
        int kk = i >> 11;                            // 0..15
        int t = kk * 32 + ((l >> 4) << 3) + j;
        int d = n * 16 + (l & 15);
        bhi[i] = f2bf_rne(tw[t * ND + d]);
    } else {
        int q = i - 32768;                           // 0..16383
        int br = q >> 13;                            // 0 user, 1 item
        int e = q & 8191;
        int j  = e & 7;
        int l  = (e >> 3) & 63;
        int n  = (e >> 9) & 3;
        int kk = e >> 11;                            // 0..3
        int k = kk * 32 + ((l >> 4) << 3) + j;       // 0..127
        int col = n * 16 + (l & 15);
        const float* W = (k < 64) ? (br ? fc_ri_w : fc_ru_w)
                                  : (br ? fc_i_w  : fc_u_w);
        unsigned short hi = f2bf_rne(W[(k & 63) * ND + col]);
        if (br) fihi[e] = hi; else fuhi[e] = hi;
    }
}

// ---------------------------------------------------------------------------
__global__ __launch_bounds__(256) void colsum_kernel(const float* __restrict__ tw,
                                                     float* __restrict__ colsum) {
    __shared__ float part[4][ND];
    int d = threadIdx.x & 63, p = threadIdx.x >> 6;
    float s = 0.f;
    for (int t = p; t < NT; t += 4) s += tw[t * ND + d];
    part[p][d] = s;
    __syncthreads();
    if (threadIdx.x < ND)
        colsum[d] = part[0][d] + part[1][d] + part[2][d] + part[3][d];
}

// pinned issue of one A row-segment (1KB contiguous per wave instruction)
#define ISSUE(i)                                                               \
    int row_##i = (i) * 4 + wave;                                              \
    row_##i = row_##i > NR - 1 ? NR - 1 : row_##i;                             \
    float4 dA_##i;                                                             \
    {                                                                          \
        const float* _p = Abase + (size_t)row_##i * NT + h * 256 + lane * 4;   \
        asm volatile("global_load_dwordx4 %0, %1, off"                         \
                     : "=v"(dA_##i) : "v"(_p) : "memory");                     \
    }

// interlocked retire+convert: the wait and the use live in ONE asm block
#define CONSUME(i, N)                                                          \
    {                                                                          \
        unsigned int _o0, _o1;                                                 \
        asm volatile("s_waitcnt vmcnt(" #N ")\n\t"                             \
                     "v_cvt_pk_bf16_f32 %0, %2, %3\n\t"                        \
                     "v_cvt_pk_bf16_f32 %1, %4, %5"                            \
                     : "=&v"(_o0), "=&v"(_o1)                                  \
                     : "v"(dA_##i.x), "v"(dA_##i.y),                           \
                       "v"(dA_##i.z), "v"(dA_##i.w)                            \
                     : "memory");                                              \
        uint2 _w; _w.x = _o0; _w.y = _o1;                                      \
        *reinterpret_cast<uint2*>(arena + row_##i * 512 +                      \
            ((lane ^ ((row_##i & 7) << 1)) * 8)) = _w;                         \
    }

// ---------------------------------------------------------------------------
// One block per (branch, batch element), 4 waves, 2 blocks/CU.
// Per K-half: 8 B gload_lds + 13 PINNED A loads issued back-to-back
// (~13KB/wave in flight), retired by interlocked vmcnt(12-i)+cvt asm,
// swizzled ds_write; then pure-LDS MFMA phase.
__global__ __launch_bounds__(256, 2) void branch_kernel(
    const int* __restrict__ user, const int* __restrict__ item,
    const float* __restrict__ user_r_topic, const float* __restrict__ item_r_topic,
    const float* __restrict__ user_embed_w, const float* __restrict__ item_embed_w,
    const float* __restrict__ user_att_w, const float* __restrict__ item_att_w,
    const unsigned short* __restrict__ bhi,
    const unsigned short* __restrict__ fuhi, const unsigned short* __restrict__ fihi,
    const float* __restrict__ fc_u_b, const float* __restrict__ fc_ru_b,
    const float* __restrict__ fc_i_b, const float* __restrict__ fc_ri_b,
    const float* __restrict__ h_u_w, const float* __restrict__ h_u_b,
    const float* __restrict__ h_i_w, const float* __restrict__ h_i_b,
    const float* __restrict__ colsum,
    float* __restrict__ u_vec, float* __restrict__ i_vec)
{
    __shared__ __align__(16) unsigned char arena[ALDS + 32768];
    __shared__ float lds_logit[NR + 2];

    const int tid = threadIdx.x, wave = tid >> 6, lane = tid & 63;
    const int g = lane >> 4, c16 = lane & 15;

    const int bb = blockIdx.x;
    const int branch = bb >> 11;          // 0 = user, 1 = item
    const int b = bb & (NB - 1);

    const int*   ids     = branch ? item           : user;
    const float* r_topic = branch ? item_r_topic   : user_r_topic;
    const float* emb_w   = branch ? item_embed_w   : user_embed_w;
    const float* att_w   = branch ? item_att_w     : user_att_w;
    const unsigned short* fhi = branch ? fihi : fuhi;
    const float* fc_a_b  = branch ? fc_i_b         : fc_u_b;
    const float* fc_r_b  = branch ? fc_ri_b        : fc_ru_b;
    const float* h_w     = branch ? h_i_w          : h_u_w;
    const float* h_b     = branch ? h_i_b          : h_u_b;
    float*       out_vec = branch ? i_vec          : u_vec;

    const int id = ids[b];
    const int rowg = wave * 16 + c16;
    const int rowc = rowg < NR ? rowg : NR - 1;
    unsigned char* blds = arena + ALDS;

    const float* Abase = r_topic + (size_t)b * NR * NT;

    f32x4 acc[4];
#pragma unroll
    for (int n = 0; n < 4; ++n) acc[n] = (f32x4){0.f, 0.f, 0.f, 0.f};

    auto kstep = [&](int kkl) {
        bf16x8 af = *reinterpret_cast<const bf16x8*>(
            arena + rowc * 512 + (((kkl * 4 + g) ^ (rowc & 7)) << 4));
#pragma unroll
        for (int n = 0; n < 4; ++n) {
            bf16x8 bh = *reinterpret_cast<const bf16x8*>(
                blds + (size_t)((kkl * 4 + n) * 64 + lane) * 16);
            acc[n] = __builtin_amdgcn_mfma_f32_16x16x32_bf16(af, bh, acc[n], 0, 0, 0);
        }
    };

    auto half_pass = [&](int h) {
        // B-half: 8 async gload_lds (32 KB)
        {
            const unsigned char* src = (const unsigned char*)bhi + (size_t)h * 32768;
#pragma unroll
            for (int i = 0; i < 8; ++i) {
                size_t off = (size_t)(i * 256 + tid) * 16;
                gload16(src + off, blds + off);
            }
        }
        // 13 pinned A loads, issued back-to-back (queue: <=8 B ops + 13 A ops)
        ISSUE(0)  ISSUE(1)  ISSUE(2)  ISSUE(3)  ISSUE(4)  ISSUE(5)  ISSUE(6)
        ISSUE(7)  ISSUE(8)  ISSUE(9)  ISSUE(10) ISSUE(11) ISSUE(12)
        // interlocked retirement: wait vmcnt(12-i) + cvt fused in one asm
        CONSUME(0, 12) CONSUME(1, 11) CONSUME(2, 10) CONSUME(3, 9)
        CONSUME(4, 8)  CONSUME(5, 7)  CONSUME(6, 6)  CONSUME(7, 5)
        CONSUME(8, 4)  CONSUME(9, 3)  CONSUME(10, 2) CONSUME(11, 1)
        CONSUME(12, 0)   // vmcnt(0): A and B all landed
        __syncthreads();                 // + lgkmcnt for ds_writes
#pragma unroll
        for (int kkl = 0; kkl < 8; ++kkl) kstep(kkl);
        __syncthreads();                 // all LDS reads done before next half
    };

    half_pass(0);
    half_pass(1);

    float (*rev)[REVP] = reinterpret_cast<float(*)[REVP]>(blds);
#pragma unroll
    for (int n = 0; n < 4; ++n)
#pragma unroll
        for (int r4 = 0; r4 < 4; ++r4) {
            int r = wave * 16 + g * 4 + r4;
            if (r < NR) rev[r][n * 16 + c16] = acc[n][r4];
        }
    // no barrier: epilogue reads only this wave's own rows

    // ---- epilogue s-matmul: s[50x64] = review@fcR + att@fcA (K=128, bf16) ----
    f32x4 s4[4];
#pragma unroll
    for (int n = 0; n < 4; ++n) s4[n] = (f32x4){0.f, 0.f, 0.f, 0.f};

#pragma unroll
    for (int kk2 = 0; kk2 < 4; ++kk2) {
        bf16x8 bh[4];
#pragma unroll
        for (int n = 0; n < 4; ++n)
            bh[n] = *(reinterpret_cast<const bf16x8*>(fhi + (size_t)(kk2 * 4 + n) * 512) + lane);
        bf16x8 ah;
        if (kk2 < 2) {
            const float* rp = &rev[rowc][kk2 * 32 + g * 8];
            ah = cvt8_rne(*reinterpret_cast<const float4*>(rp),
                          *reinterpret_cast<const float4*>(rp + 4));
        } else {
            const float* ap = att_w + (size_t)id * ND + (kk2 - 2) * 32 + g * 8;
            ah = cvt8_rne(*reinterpret_cast<const float4*>(ap),
                          *reinterpret_cast<const float4*>(ap + 4));
        }
#pragma unroll
        for (int n = 0; n < 4; ++n)
            s4[n] = __builtin_amdgcn_mfma_f32_16x16x32_bf16(ah, bh[n], s4[n], 0, 0, 0);
    }

    // bias + relu + dot with h_w, then 16-lane reduce -> logits
    const float hb = h_b[0];
    float p0 = 0.f, p1 = 0.f, p2 = 0.f, p3 = 0.f;
#pragma unroll
    for (int n = 0; n < 4; ++n) {
        float hwn = h_w[n * 16 + c16];
        float bs = fc_r_b[n * 16 + c16] + fc_a_b[n * 16 + c16];
        p0 = fmaf(fmaxf(s4[n][0] + bs, 0.f), hwn, p0);
        p1 = fmaf(fmaxf(s4[n][1] + bs, 0.f), hwn, p1);
        p2 = fmaf(fmaxf(s4[n][2] + bs, 0.f), hwn, p2);
        p3 = fmaf(fmaxf(s4[n][3] + bs, 0.f), hwn, p3);
    }
#pragma unroll
    for (int off = 1; off < 16; off <<= 1) {
        p0 += __shfl_xor(p0, off);
        p1 += __shfl_xor(p1, off);
        p2 += __shfl_xor(p2, off);
        p3 += __shfl_xor(p3, off);
    }
    if (c16 == 0) {
        int rb = wave * 16 + g * 4;
        if (rb + 0 < NR) lds_logit[rb + 0] = p0 + hb;
        if (rb + 1 < NR) lds_logit[rb + 1] = p1 + hb;
        if (rb + 2 < NR) lds_logit[rb + 2] = p2 + hb;
        if (rb + 3 < NR) lds_logit[rb + 3] = p3 + hb;
    }
    __syncthreads();   // publish rev rows + logits to wave 0

    // softmax + pooling + colsum scale + emb add (wave 0)
    if (wave == 0) {
        float m = -1e30f;
        for (int r = 0; r < NR; ++r) m = fmaxf(m, lds_logit[r]);
        float sum = 0.f;
        for (int r = 0; r < NR; ++r) sum += __expf(lds_logit[r] - m);
        float inv = 1.f / sum;
        float feat = 0.f;
        for (int r = 0; r < NR; ++r)
            feat = fmaf(__expf(lds_logit[r] - m), rev[r][lane], feat);
        feat *= inv;
        out_vec[(size_t)b * ND + lane] = feat * colsum[lane] + emb_w[(size_t)id * ND + lane];
    }
}

// ---------------------------------------------------------------------------
__global__ __launch_bounds__(64) void final_kernel(
    const float* __restrict__ u_vec, const float* __restrict__ i_vec,
    const float* __restrict__ fc_pre_w, const float* __restrict__ fc_pre_b,
    float* __restrict__ out)
{
    int b = blockIdx.x, lane = threadIdx.x;
    float v = u_vec[(size_t)b * ND + lane] * fc_pre_w[lane]
            + i_vec[(size_t)b * ND + lane] * fc_pre_w[ND + lane];
#pragma unroll
    for (int off = 32; off; off >>= 1) v += __shfl_xor(v, off);
    if (lane == 0) out[b] = fmaxf(v + fc_pre_b[0], 0.f);
}

// ---------------------------------------------------------------------------
extern "C" void kernel_launch(void* const* d_in, const int* in_sizes, int n_in,
                              void* d_out, int out_size, void* d_ws, size_t ws_size,
                              hipStream_t stream) {
    (void)in_sizes; (void)n_in; (void)out_size; (void)ws_size;

    const int*   user         = (const int*)d_in[0];
    const int*   item         = (const int*)d_in[1];
    const float* user_r_topic = (const float*)d_in[2];
    const float* item_r_topic = (const float*)d_in[3];
    const float* user_embed_w = (const float*)d_in[4];
    const float* item_embed_w = (const float*)d_in[5];
    const float* user_att_w   = (const float*)d_in[6];
    const float* item_att_w   = (const float*)d_in[7];
    const float* topic_w      = (const float*)d_in[8];
    const float* fc_u_w       = (const float*)d_in[9];
    const float* fc_u_b       = (const float*)d_in[10];
    const float* fc_ru_w      = (const float*)d_in[11];
    const float* fc_ru_b      = (const float*)d_in[12];
    const float* fc_i_w       = (const float*)d_in[13];
    const float* fc_i_b       = (const float*)d_in[14];
    const float* fc_ri_w      = (const float*)d_in[15];
    const float* fc_ri_b      = (const float*)d_in[16];
    const float* h_u_w        = (const float*)d_in[17];
    const float* h_u_b        = (const float*)d_in[18];
    const float* h_i_w        = (const float*)d_in[19];
    const float* h_i_b        = (const float*)d_in[20];
    const float* fc_pre_w     = (const float*)d_in[21];
    const float* fc_pre_b     = (const float*)d_in[22];

    // workspace layout
    unsigned short* bhi  = (unsigned short*)d_ws;      // 32768
    unsigned short* fuhi = bhi + 32768;                // 8192
    unsigned short* fihi = fuhi + 8192;                // 8192
    float* colsum = (float*)(fihi + 8192);             // 64
    float* u_vec  = colsum + 64;                       // NB*ND
    float* i_vec  = u_vec + NB * ND;                   // NB*ND

    prep_kernel<<<192, 256, 0, stream>>>(topic_w, fc_u_w, fc_ru_w, fc_i_w, fc_ri_w,
                                         bhi, fuhi, fihi);
    colsum_kernel<<<1, 256, 0, stream>>>(topic_w, colsum);

    branch_kernel<<<2 * NB, 256, 0, stream>>>(
        user, item, user_r_topic, item_r_topic,
        user_embed_w, item_embed_w, user_att_w, item_att_w,
        bhi, fuhi, fihi,
        fc_u_b, fc_ru_b, fc_i_b, fc_ri_b,
        h_u_w, h_u_b, h_i_w, h_i_b,
        colsum, u_vec, i_vec);

    final_kernel<<<NB, 64, 0, stream>>>(u_vec, i_vec, fc_pre_w, fc_pre_b,
                                        (float*)d_out);
}